// Round 1
// baseline (6766.503 us; speedup 1.0000x reference)
//
#include <hip/hip_runtime.h>
#include <math.h>

#define B_  2
#define T_  2048
#define D_  512
#define L_  6
#define FF_ 2048
#define V_  32000
#define S_  8
#define DS_ 32
#define K_  15
#define M_  (B_*T_)   // 4096 tokens

__device__ __forceinline__ float sigmoidf_(float x) { return 1.0f / (1.0f + expf(-x)); }
__device__ __forceinline__ float siluf_(float x)    { return x / (1.0f + expf(-x)); }

// ---------------- zero init for memory state ----------------
__global__ void zero512_kernel(float* p) { p[threadIdx.x] = 0.0f; }

// ---------------- rmsnorm: one wave per row (D=512 -> 8 floats/lane) ----------------
__global__ __launch_bounds__(256) void rms_kernel(const float* __restrict__ in,
                                                  const float* __restrict__ w,
                                                  float* __restrict__ out) {
  int wid = threadIdx.x >> 6, lane = threadIdx.x & 63;
  int row = (blockIdx.x << 2) + wid;
  const float* x = in + (size_t)row * D_ + lane * 8;
  float4 v0 = *(const float4*)x;
  float4 v1 = *(const float4*)(x + 4);
  float ss = v0.x*v0.x + v0.y*v0.y + v0.z*v0.z + v0.w*v0.w
           + v1.x*v1.x + v1.y*v1.y + v1.z*v1.z + v1.w*v1.w;
#pragma unroll
  for (int off = 32; off > 0; off >>= 1) ss += __shfl_xor(ss, off);
  float sc = 1.0f / sqrtf(ss * (1.0f / D_) + 1e-6f);
  const float* wp = w + lane * 8;
  float4 w0 = *(const float4*)wp, w1 = *(const float4*)(wp + 4);
  float* o = out + (size_t)row * D_ + lane * 8;
  float4 r0, r1;
  r0.x = v0.x * sc * w0.x; r0.y = v0.y * sc * w0.y;
  r0.z = v0.z * sc * w0.z; r0.w = v0.w * sc * w0.w;
  r1.x = v1.x * sc * w1.x; r1.y = v1.y * sc * w1.y;
  r1.z = v1.z * sc * w1.z; r1.w = v1.w * sc * w1.w;
  *(float4*)o = r0; *(float4*)(o + 4) = r1;
}

// ---------------- embedding lookup + rmsnorm ----------------
__global__ __launch_bounds__(256) void embed_rms_kernel(const int* __restrict__ tokens,
                                                        const float* __restrict__ embed,
                                                        const float* __restrict__ w,
                                                        float* __restrict__ out) {
  int wid = threadIdx.x >> 6, lane = threadIdx.x & 63;
  int row = (blockIdx.x << 2) + wid;
  int tok = tokens[row];
  const float* x = embed + (size_t)tok * D_ + lane * 8;
  float4 v0 = *(const float4*)x;
  float4 v1 = *(const float4*)(x + 4);
  float ss = v0.x*v0.x + v0.y*v0.y + v0.z*v0.z + v0.w*v0.w
           + v1.x*v1.x + v1.y*v1.y + v1.z*v1.z + v1.w*v1.w;
#pragma unroll
  for (int off = 32; off > 0; off >>= 1) ss += __shfl_xor(ss, off);
  float sc = 1.0f / sqrtf(ss * (1.0f / D_) + 1e-6f);
  const float* wp = w + lane * 8;
  float4 w0 = *(const float4*)wp, w1 = *(const float4*)(wp + 4);
  float* o = out + (size_t)row * D_ + lane * 8;
  float4 r0, r1;
  r0.x = v0.x * sc * w0.x; r0.y = v0.y * sc * w0.y;
  r0.z = v0.z * sc * w0.z; r0.w = v0.w * sc * w0.w;
  r1.x = v1.x * sc * w1.x; r1.y = v1.y * sc * w1.y;
  r1.z = v1.z * sc * w1.z; r1.w = v1.w * sc * w1.w;
  *(float4*)o = r0; *(float4*)(o + 4) = r1;
}

// ---------------- GEMM config A: 128x128 tile, BK=16, 256 thr, 8x8/thread ----------------
// C[m,n] = sum_k A[m,k]*B[n,k];  A: MxK row-major, B: NxK row-major.
// MODE 0: store. MODE 1: sigmoid where global col < nsig, store.
template<int MODE>
__global__ __launch_bounds__(256) void gemm_a(const float* __restrict__ A,
                                              const float* __restrict__ Bm,
                                              float* __restrict__ C,
                                              int N, int K, int nsig) {
  __shared__ float As[16][132];
  __shared__ float Bs[16][132];
  const int tid = threadIdx.x;
  const int row0 = blockIdx.x * 128;
  const int col0 = blockIdx.y * 128;
  const int lr = tid >> 1, lk = (tid & 1) * 8;
  const float* Ap = A  + (size_t)(row0 + lr) * K + lk;
  const float* Bp = Bm + (size_t)(col0 + lr) * K + lk;
  float4 a0 = *(const float4*)Ap, a1 = *(const float4*)(Ap + 4);
  float4 b0 = *(const float4*)Bp, b1 = *(const float4*)(Bp + 4);
  float acc[8][8];
#pragma unroll
  for (int i = 0; i < 8; i++)
#pragma unroll
    for (int j = 0; j < 8; j++) acc[i][j] = 0.0f;
  const int r = tid >> 4, c = tid & 15;
  for (int k0 = 0; k0 < K; k0 += 16) {
#pragma unroll
    for (int j = 0; j < 4; j++) {
      As[lk + j][lr]     = ((const float*)&a0)[j];
      As[lk + 4 + j][lr] = ((const float*)&a1)[j];
      Bs[lk + j][lr]     = ((const float*)&b0)[j];
      Bs[lk + 4 + j][lr] = ((const float*)&b1)[j];
    }
    __syncthreads();
    if (k0 + 16 < K) {
      Ap += 16; Bp += 16;
      a0 = *(const float4*)Ap; a1 = *(const float4*)(Ap + 4);
      b0 = *(const float4*)Bp; b1 = *(const float4*)(Bp + 4);
    }
#pragma unroll
    for (int kk = 0; kk < 16; kk++) {
      float av[8], bv[8];
      *(float4*)&av[0] = *(const float4*)&As[kk][r * 8];
      *(float4*)&av[4] = *(const float4*)&As[kk][r * 8 + 4];
      *(float4*)&bv[0] = *(const float4*)&Bs[kk][c * 4];
      *(float4*)&bv[4] = *(const float4*)&Bs[kk][c * 4 + 64];
#pragma unroll
      for (int i = 0; i < 8; i++)
#pragma unroll
        for (int j = 0; j < 8; j++)
          acc[i][j] = fmaf(av[i], bv[j], acc[i][j]);
    }
    __syncthreads();
  }
#pragma unroll
  for (int i = 0; i < 8; i++) {
    float* Cr = C + (size_t)(row0 + (r << 3) + i) * N + col0;
#pragma unroll
    for (int g = 0; g < 2; g++) {
      int cb = (c << 2) + g * 64;
      float4 v;
      v.x = acc[i][g * 4 + 0]; v.y = acc[i][g * 4 + 1];
      v.z = acc[i][g * 4 + 2]; v.w = acc[i][g * 4 + 3];
      if (MODE == 1) {
        if (col0 + cb < nsig) {
          v.x = sigmoidf_(v.x); v.y = sigmoidf_(v.y);
          v.z = sigmoidf_(v.z); v.w = sigmoidf_(v.w);
        }
      }
      *(float4*)(Cr + cb) = v;
    }
  }
}

// ---------------- GEMM config B: 128x64 tile, BK=16, 256 thr, 8x4/thread ----------------
// MODE 2: C += A*B^T (residual add).  MODE 3: C = silu(A*Bg^T) * (A*Bu^T) (fused FFN).
template<int MODE>
__global__ __launch_bounds__(256) void gemm_b(const float* __restrict__ A,
                                              const float* __restrict__ Bg,
                                              const float* __restrict__ Bu,
                                              float* __restrict__ C,
                                              int N, int K) {
  __shared__ float As[16][132];
  __shared__ float Bs[16][68];
  __shared__ float Bs2[16][68];
  const int tid = threadIdx.x;
  const int row0 = blockIdx.x * 128;
  const int col0 = blockIdx.y * 64;
  const int lr = tid >> 1, lk = (tid & 1) * 8;
  const int bn = tid >> 2, bk = (tid & 3) * 4;
  const float* Ap = A  + (size_t)(row0 + lr) * K + lk;
  const float* Bp = Bg + (size_t)(col0 + bn) * K + bk;
  float4 a0 = *(const float4*)Ap, a1 = *(const float4*)(Ap + 4);
  float4 b0 = *(const float4*)Bp;
  float4 b2;
  const float* Bp2 = nullptr;
  if (MODE == 3) {
    Bp2 = Bu + (size_t)(col0 + bn) * K + bk;
    b2 = *(const float4*)Bp2;
  }
  float accg[8][4], accu[8][4];
#pragma unroll
  for (int i = 0; i < 8; i++)
#pragma unroll
    for (int j = 0; j < 4; j++) { accg[i][j] = 0.0f; accu[i][j] = 0.0f; }
  const int r = tid >> 4, c = tid & 15;
  for (int k0 = 0; k0 < K; k0 += 16) {
#pragma unroll
    for (int j = 0; j < 4; j++) {
      As[lk + j][lr]     = ((const float*)&a0)[j];
      As[lk + 4 + j][lr] = ((const float*)&a1)[j];
      Bs[bk + j][bn]     = ((const float*)&b0)[j];
      if (MODE == 3) Bs2[bk + j][bn] = ((const float*)&b2)[j];
    }
    __syncthreads();
    if (k0 + 16 < K) {
      Ap += 16; Bp += 16;
      a0 = *(const float4*)Ap; a1 = *(const float4*)(Ap + 4);
      b0 = *(const float4*)Bp;
      if (MODE == 3) { Bp2 += 16; b2 = *(const float4*)Bp2; }
    }
#pragma unroll
    for (int kk = 0; kk < 16; kk++) {
      float av[8], bg4[4], bu4[4];
      *(float4*)&av[0] = *(const float4*)&As[kk][r * 8];
      *(float4*)&av[4] = *(const float4*)&As[kk][r * 8 + 4];
      *(float4*)&bg4[0] = *(const float4*)&Bs[kk][c * 4];
      if (MODE == 3) *(float4*)&bu4[0] = *(const float4*)&Bs2[kk][c * 4];
#pragma unroll
      for (int i = 0; i < 8; i++)
#pragma unroll
        for (int j = 0; j < 4; j++) {
          accg[i][j] = fmaf(av[i], bg4[j], accg[i][j]);
          if (MODE == 3) accu[i][j] = fmaf(av[i], bu4[j], accu[i][j]);
        }
    }
    __syncthreads();
  }
#pragma unroll
  for (int i = 0; i < 8; i++) {
    float* Cr = C + (size_t)(row0 + (r << 3) + i) * N + col0 + (c << 2);
    float4 v;
    if (MODE == 3) {
      v.x = siluf_(accg[i][0]) * accu[i][0];
      v.y = siluf_(accg[i][1]) * accu[i][1];
      v.z = siluf_(accg[i][2]) * accu[i][2];
      v.w = siluf_(accg[i][3]) * accu[i][3];
    } else {
      float4 old = *(const float4*)Cr;
      v.x = accg[i][0] + old.x; v.y = accg[i][1] + old.y;
      v.z = accg[i][2] + old.z; v.w = accg[i][3] + old.w;
    }
    *(float4*)Cr = v;
  }
}

// ---------------- depthwise causal conv (K=15) + gate multiply ----------------
// gv: (M,1024): gate(sigmoided)=[0:512), val=[512:1024).  co: (M,512)
__global__ __launch_bounds__(256) void conv_gate_kernel(const float* __restrict__ gv,
                                                        const float* __restrict__ cw,
                                                        float* __restrict__ co) {
  int d = ((blockIdx.x & 1) << 8) + threadIdx.x;
  int bt = blockIdx.x >> 1;
  int t = bt & (T_ - 1);
  float w[K_];
#pragma unroll
  for (int k = 0; k < K_; k++) w[k] = cw[d * K_ + k];
  const float* val = gv + (size_t)bt * 1024 + 512 + d;
  float s = 0.0f;
#pragma unroll
  for (int k = 0; k < K_; k++) {
    int tt = t - (K_ - 1) + k;
    if (tt >= 0) s = fmaf(w[k], val[(tt - t) * 1024], s);
  }
  float gate = gv[(size_t)bt * 1024 + d];
  co[(size_t)bt * 512 + d] = s * gate;
}

// ---------------- per-token g(8,sigmoid) / v(32) / rw(8,softmax) ----------------
__global__ __launch_bounds__(256) void gvr_kernel(const float* __restrict__ h,
                                                  const float* __restrict__ wg,
                                                  const float* __restrict__ wv,
                                                  const float* __restrict__ rq,
                                                  float* __restrict__ garr,
                                                  float* __restrict__ varr,
                                                  float* __restrict__ rwarr) {
  __shared__ float sm[4][48];
  int w = threadIdx.x >> 6, lane = threadIdx.x & 63;
  int tok = (blockIdx.x << 2) + w;
  const float* x = h + (size_t)tok * D_ + lane * 8;
  float4 h0 = *(const float4*)x, h1 = *(const float4*)(x + 4);
  float hreg[8] = {h0.x, h0.y, h0.z, h0.w, h1.x, h1.y, h1.z, h1.w};
  float keep = 0.0f;
  for (int o = 0; o < 48; o++) {
    const float* Wr = (o < 8) ? (wg + o * D_)
                    : (o < 40 ? (wv + (o - 8) * D_) : (rq + (o - 40) * D_));
    const float* wp = Wr + lane * 8;
    float p = 0.0f;
#pragma unroll
    for (int j = 0; j < 8; j++) p = fmaf(hreg[j], wp[j], p);
#pragma unroll
    for (int off = 32; off > 0; off >>= 1) p += __shfl_xor(p, off);
    if (lane == o) keep = p;
  }
  if (lane < 48) sm[w][lane] = keep;
  __syncthreads();
  if (lane < 8)  garr[(size_t)tok * 8 + lane]  = sigmoidf_(sm[w][lane]);
  if (lane < 32) varr[(size_t)tok * 32 + lane] = sm[w][8 + lane];
  if (lane < 8) {
    float q = sm[w][40 + lane];
    float mx = sm[w][40];
#pragma unroll
    for (int j = 1; j < 8; j++) mx = fmaxf(mx, sm[w][40 + j]);
    float sum = 0.0f;
#pragma unroll
    for (int j = 0; j < 8; j++) sum += expf(sm[w][40 + j] - mx);
    rwarr[(size_t)tok * 8 + lane] = expf(q - mx) / sum;
  }
}

// ---------------- sequential story-memory scan over T, fused read-weighting ----------------
// thread = (s,ds); m_t = (1-g)*m + g*v;  rf[t, s*32+ds] = rw[t,s]*m_t
__global__ __launch_bounds__(256) void scan_kernel(const float* __restrict__ garr,
                                                   const float* __restrict__ varr,
                                                   const float* __restrict__ rwarr,
                                                   float* __restrict__ rf,
                                                   float* __restrict__ mem) {
  int b = blockIdx.x;
  int tid = threadIdx.x;
  int s = tid >> 5, ds = tid & 31;
  float m = mem[b * 256 + tid];
  const float* gp = garr + (size_t)b * T_ * 8;
  const float* vp = varr + (size_t)b * T_ * 32;
  const float* rp = rwarr + (size_t)b * T_ * 8;
  float* rfp = rf + (size_t)b * T_ * 256 + tid;
  float gn = gp[s], vn = vp[ds], rn = rp[s];
  for (int t = 0; t < T_; t++) {
    float gc = gn, vc = vn, rc = rn;
    if (t + 1 < T_) {
      gn = gp[(t + 1) * 8 + s];
      vn = vp[(t + 1) * 32 + ds];
      rn = rp[(t + 1) * 8 + s];
    }
    m = fmaf(m, 1.0f - gc, gc * vc);
    rfp[(size_t)t * 256] = rc * m;
  }
  mem[b * 256 + tid] = m;
}

// ---------------- launch ----------------
extern "C" void kernel_launch(void* const* d_in, const int* in_sizes, int n_in,
                              void* d_out, int out_size, void* d_ws, size_t ws_size,
                              hipStream_t stream) {
  const int*   tokens     = (const int*)d_in[0];
  const float* embed      = (const float*)d_in[1];
  const float* ln_in      = (const float*)d_in[2];
  const float* ln1        = (const float*)d_in[3];
  const float* mixer_up   = (const float*)d_in[4];
  const float* conv_w     = (const float*)d_in[5];
  const float* mixer_down = (const float*)d_in[6];
  const float* ln_mem     = (const float*)d_in[7];
  const float* wg         = (const float*)d_in[8];
  const float* wv         = (const float*)d_in[9];
  const float* rq         = (const float*)d_in[10];
  const float* ro         = (const float*)d_in[11];
  const float* ln2        = (const float*)d_in[12];
  const float* Wgf        = (const float*)d_in[13];
  const float* Wuf        = (const float*)d_in[14];
  const float* Wof        = (const float*)d_in[15];
  const float* ln_out     = (const float*)d_in[16];
  float* out = (float*)d_out;

  float* p = (float*)d_ws;
  float* bx   = p; p += (size_t)M_ * D_;       // residual stream
  float* bh   = p; p += (size_t)M_ * D_;       // rmsnorm output
  float* bgv  = p; p += (size_t)M_ * 2 * D_;   // gate|val
  float* bco  = p; p += (size_t)M_ * D_;       // gated conv out
  float* bup  = p; p += (size_t)M_ * FF_;      // fused silu*up
  float* bg   = p; p += (size_t)M_ * S_;       // write gate
  float* bv   = p; p += (size_t)M_ * DS_;      // write value
  float* brw  = p; p += (size_t)M_ * S_;       // read weights
  float* brf  = p; p += (size_t)M_ * S_ * DS_; // weighted memory readout
  float* bmem = p; p += B_ * S_ * DS_;         // carried memory state

  zero512_kernel<<<1, 512, 0, stream>>>(bmem);
  embed_rms_kernel<<<M_ / 4, 256, 0, stream>>>(tokens, embed, ln_in, bx);

  for (int i = 0; i < L_; i++) {
    rms_kernel<<<M_ / 4, 256, 0, stream>>>(bx, ln1 + i * D_, bh);
    gemm_a<1><<<dim3(M_ / 128, (2 * D_) / 128), 256, 0, stream>>>(
        bh, mixer_up + (size_t)i * 2 * D_ * D_, bgv, 2 * D_, D_, D_);
    conv_gate_kernel<<<M_ * 2, 256, 0, stream>>>(bgv, conv_w + (size_t)i * D_ * K_, bco);
    gemm_b<2><<<dim3(M_ / 128, D_ / 64), 256, 0, stream>>>(
        bco, mixer_down + (size_t)i * D_ * D_, nullptr, bx, D_, D_);
    rms_kernel<<<M_ / 4, 256, 0, stream>>>(bx, ln_mem + i * D_, bh);
    gvr_kernel<<<M_ / 4, 256, 0, stream>>>(bh, wg + (size_t)i * S_ * D_,
                                           wv + (size_t)i * DS_ * D_,
                                           rq + (size_t)i * S_ * D_, bg, bv, brw);
    scan_kernel<<<B_, 256, 0, stream>>>(bg, bv, brw, brf, bmem);
    gemm_b<2><<<dim3(M_ / 128, D_ / 64), 256, 0, stream>>>(
        brf, ro + (size_t)i * D_ * S_ * DS_, nullptr, bx, D_, S_ * DS_);
    rms_kernel<<<M_ / 4, 256, 0, stream>>>(bx, ln2 + i * D_, bh);
    gemm_b<3><<<dim3(M_ / 128, FF_ / 64), 256, 0, stream>>>(
        bh, Wgf + (size_t)i * FF_ * D_, Wuf + (size_t)i * FF_ * D_, bup, FF_, D_);
    gemm_b<2><<<dim3(M_ / 128, D_ / 64), 256, 0, stream>>>(
        bup, Wof + (size_t)i * D_ * FF_, nullptr, bx, D_, FF_);
  }

  rms_kernel<<<M_ / 4, 256, 0, stream>>>(bx, ln_out, bh);
  gemm_a<0><<<dim3(M_ / 128, V_ / 128), 256, 0, stream>>>(bh, embed, out, V_, D_, 0);
}

// Round 2
// 4661.263 us; speedup vs baseline: 1.4516x; 1.4516x over previous
//
#include <hip/hip_runtime.h>
#include <math.h>

#define B_  2
#define T_  2048
#define D_  512
#define L_  6
#define FF_ 2048
#define V_  32000
#define S_  8
#define DS_ 32
#define K_  15
#define M_  (B_*T_)   // 4096 tokens

typedef __bf16 bf16x8 __attribute__((ext_vector_type(8)));
typedef float  f32x4  __attribute__((ext_vector_type(4)));

__device__ __forceinline__ float sigmoidf_(float x) { return 1.0f / (1.0f + expf(-x)); }
__device__ __forceinline__ float siluf_(float x)    { return x / (1.0f + expf(-x)); }

__device__ __forceinline__ ushort f2bf(float f) {
  uint u = __float_as_uint(f);
  return (ushort)((u + 0x7FFFu + ((u >> 16) & 1u)) >> 16);
}
__device__ __forceinline__ float bf2f(ushort h) { return __uint_as_float(((uint)h) << 16); }
__device__ __forceinline__ void split2(float x, ushort& h, ushort& l) {
  h = f2bf(x);
  l = f2bf(x - bf2f(h));
}
__device__ __forceinline__ void gl16(const void* g, void* l) {
  __builtin_amdgcn_global_load_lds((const __attribute__((address_space(1))) void*)g,
                                   (__attribute__((address_space(3))) void*)l, 16, 0, 0);
}

// ---------------- zero init for memory state ----------------
__global__ void zero512_kernel(float* p) { p[threadIdx.x] = 0.0f; }

// ---------------- embedding lookup + rmsnorm (fp32 out: residual base) ----------------
__global__ __launch_bounds__(256) void embed_rms_kernel(const int* __restrict__ tokens,
                                                        const float* __restrict__ embed,
                                                        const float* __restrict__ w,
                                                        float* __restrict__ out) {
  int wid = threadIdx.x >> 6, lane = threadIdx.x & 63;
  int row = (blockIdx.x << 2) + wid;
  int tok = tokens[row];
  const float* x = embed + (size_t)tok * D_ + lane * 8;
  float4 v0 = *(const float4*)x;
  float4 v1 = *(const float4*)(x + 4);
  float ss = v0.x*v0.x + v0.y*v0.y + v0.z*v0.z + v0.w*v0.w
           + v1.x*v1.x + v1.y*v1.y + v1.z*v1.z + v1.w*v1.w;
#pragma unroll
  for (int off = 32; off > 0; off >>= 1) ss += __shfl_xor(ss, off);
  float sc = 1.0f / sqrtf(ss * (1.0f / D_) + 1e-6f);
  const float* wp = w + lane * 8;
  float4 w0 = *(const float4*)wp, w1 = *(const float4*)(wp + 4);
  float* o = out + (size_t)row * D_ + lane * 8;
  float4 r0, r1;
  r0.x = v0.x * sc * w0.x; r0.y = v0.y * sc * w0.y;
  r0.z = v0.z * sc * w0.z; r0.w = v0.w * sc * w0.w;
  r1.x = v1.x * sc * w1.x; r1.y = v1.y * sc * w1.y;
  r1.z = v1.z * sc * w1.z; r1.w = v1.w * sc * w1.w;
  *(float4*)o = r0; *(float4*)(o + 4) = r1;
}

// ---------------- rmsnorm -> bf16 hi/lo planes ----------------
__global__ __launch_bounds__(256) void rms_split_kernel(const float* __restrict__ in,
                                                        const float* __restrict__ w,
                                                        ushort* __restrict__ oh,
                                                        ushort* __restrict__ ol) {
  int wid = threadIdx.x >> 6, lane = threadIdx.x & 63;
  int row = (blockIdx.x << 2) + wid;
  const float* x = in + (size_t)row * D_ + lane * 8;
  float4 v0 = *(const float4*)x;
  float4 v1 = *(const float4*)(x + 4);
  float ss = v0.x*v0.x + v0.y*v0.y + v0.z*v0.z + v0.w*v0.w
           + v1.x*v1.x + v1.y*v1.y + v1.z*v1.z + v1.w*v1.w;
#pragma unroll
  for (int off = 32; off > 0; off >>= 1) ss += __shfl_xor(ss, off);
  float sc = 1.0f / sqrtf(ss * (1.0f / D_) + 1e-6f);
  const float* wp = w + lane * 8;
  float4 w0 = *(const float4*)wp, w1 = *(const float4*)(wp + 4);
  float y[8];
  y[0] = v0.x * sc * w0.x; y[1] = v0.y * sc * w0.y;
  y[2] = v0.z * sc * w0.z; y[3] = v0.w * sc * w0.w;
  y[4] = v1.x * sc * w1.x; y[5] = v1.y * sc * w1.y;
  y[6] = v1.z * sc * w1.z; y[7] = v1.w * sc * w1.w;
  ushort h8[8], l8[8];
#pragma unroll
  for (int j = 0; j < 8; j++) split2(y[j], h8[j], l8[j]);
  size_t off = (size_t)row * D_ + lane * 8;
  *(uint4*)(oh + off) = *(uint4*)h8;
  *(uint4*)(ol + off) = *(uint4*)l8;
}

// ---------------- generic fp32 -> hi/lo split (vectorized x4) ----------------
__global__ __launch_bounds__(256) void split4_kernel(const float* __restrict__ in,
                                                     ushort* __restrict__ hi,
                                                     ushort* __restrict__ lo, int n4) {
  int i = blockIdx.x * 256 + threadIdx.x;
  if (i >= n4) return;
  float4 v = ((const float4*)in)[i];
  ushort h[4], l[4];
  split2(v.x, h[0], l[0]); split2(v.y, h[1], l[1]);
  split2(v.z, h[2], l[2]); split2(v.w, h[3], l[3]);
  ((ushort4*)hi)[i] = *(ushort4*)h;
  ((ushort4*)lo)[i] = *(ushort4*)l;
}

// ---------------- per-layer weight split (all 6 tensors, one launch) ----------------
// float4-unit block ranges: mu 512 | md 256 | ro 128 | wgf 1024 | wuf 1024 | wof 1024
__global__ __launch_bounds__(256) void wsplit_kernel(const float* __restrict__ mu,
                                                     const float* __restrict__ md,
                                                     const float* __restrict__ rw,
                                                     const float* __restrict__ gf,
                                                     const float* __restrict__ uf,
                                                     const float* __restrict__ of,
                                                     ushort* muh, ushort* mul2,
                                                     ushort* mdh, ushort* mdl,
                                                     ushort* rh,  ushort* rl,
                                                     ushort* fh,  ushort* fl,
                                                     ushort* oh,  ushort* ol) {
  int b = blockIdx.x;
  const float* src; ushort *dh, *dl; int base;
  if      (b < 512)  { src = mu; dh = muh; dl = mul2; base = 0; }
  else if (b < 768)  { src = md; dh = mdh; dl = mdl;  base = 512; }
  else if (b < 896)  { src = rw; dh = rh;  dl = rl;   base = 768; }
  else if (b < 1920) { src = gf; dh = fh;  dl = fl;   base = 896; }
  else if (b < 2944) { src = uf; dh = fh + (size_t)FF_*D_; dl = fl + (size_t)FF_*D_; base = 1920; }
  else               { src = of; dh = oh;  dl = ol;   base = 2944; }
  int i = (b - base) * 256 + threadIdx.x;
  float4 v = ((const float4*)src)[i];
  ushort h[4], l[4];
  split2(v.x, h[0], l[0]); split2(v.y, h[1], l[1]);
  split2(v.z, h[2], l[2]); split2(v.w, h[3], l[3]);
  ((ushort4*)dh)[i] = *(ushort4*)h;
  ((ushort4*)dl)[i] = *(ushort4*)l;
}

// ---------------- MFMA GEMM with hi/lo split: C = A*B^T (+ fusion modes) ----------------
// A: M x K (hi/lo bf16 planes), B: N x K (hi/lo bf16 planes), C: M x N fp32.
// Tile BM x 128, BK=32, 256 threads = 4 waves (2x2), mfma_f32_16x16x32_bf16.
// MODE 0: store. MODE 1: sigmoid where col < nsig. MODE 2: C += result.
template<int MODE, int BM>
__global__ __launch_bounds__(256) void gemm_m(const ushort* __restrict__ Ah,
                                              const ushort* __restrict__ Al,
                                              const ushort* __restrict__ Bh,
                                              const ushort* __restrict__ Bl,
                                              float* __restrict__ C,
                                              int N, int K, int nsig) {
  constexpr int MI = BM / 32;                 // fragment rows per wave
  __shared__ ushort sm[2 * BM * 32 + 8192];   // Ah | Al | Bh | Bl tiles
  const int tid  = threadIdx.x;
  const int row0 = blockIdx.x * BM;
  const int col0 = blockIdx.y * 128;
  const int wave = tid >> 6, lane = tid & 63;
  const int wrr = (wave >> 1) * (BM / 2);
  const int wcc = (wave & 1) * 64;
  const int srow = tid >> 2;                  // staging row within 64-row chunk
  const int sslot = (tid & 3) * 8;            // staging k-slot (8 bf16 = 16B)
  const int t16 = tid * 8;                    // ushort offset of this thread's 16B
  const int arow = wrr + (lane & 15);
  const int brow = wcc + (lane & 15);
  const int koff = (lane >> 4) * 8;
  const ushort* sAh = sm;
  const ushort* sAl = sm + BM * 32;
  const ushort* sBh = sm + 2 * BM * 32;
  const ushort* sBl = sm + 2 * BM * 32 + 4096;

  f32x4 acc[MI][4] = {};

  for (int k0 = 0; k0 < K; k0 += 32) {
    __syncthreads();   // previous iteration's frag reads complete
#pragma unroll
    for (int j = 0; j < BM / 64; j++) {
      size_t g = (size_t)(row0 + j * 64 + srow) * K + k0 + sslot;
      gl16(Ah + g, (void*)(sm + j * 2048 + t16));
      gl16(Al + g, (void*)(sm + BM * 32 + j * 2048 + t16));
    }
#pragma unroll
    for (int j = 0; j < 2; j++) {
      size_t g = (size_t)(col0 + j * 64 + srow) * K + k0 + sslot;
      gl16(Bh + g, (void*)(sm + 2 * BM * 32 + j * 2048 + t16));
      gl16(Bl + g, (void*)(sm + 2 * BM * 32 + 4096 + j * 2048 + t16));
    }
    __syncthreads();   // vmcnt(0) drain: tiles ready
    bf16x8 fah[MI], fal[MI], fbh[4], fbl[4];
#pragma unroll
    for (int mi = 0; mi < MI; mi++) {
      fah[mi] = *(const bf16x8*)(sAh + (arow + mi * 16) * 32 + koff);
      fal[mi] = *(const bf16x8*)(sAl + (arow + mi * 16) * 32 + koff);
    }
#pragma unroll
    for (int ni = 0; ni < 4; ni++) {
      fbh[ni] = *(const bf16x8*)(sBh + (brow + ni * 16) * 32 + koff);
      fbl[ni] = *(const bf16x8*)(sBl + (brow + ni * 16) * 32 + koff);
    }
#pragma unroll
    for (int mi = 0; mi < MI; mi++)
#pragma unroll
      for (int ni = 0; ni < 4; ni++)
        acc[mi][ni] = __builtin_amdgcn_mfma_f32_16x16x32_bf16(fah[mi], fbh[ni], acc[mi][ni], 0, 0, 0);
#pragma unroll
    for (int mi = 0; mi < MI; mi++)
#pragma unroll
      for (int ni = 0; ni < 4; ni++)
        acc[mi][ni] = __builtin_amdgcn_mfma_f32_16x16x32_bf16(fal[mi], fbh[ni], acc[mi][ni], 0, 0, 0);
#pragma unroll
    for (int mi = 0; mi < MI; mi++)
#pragma unroll
      for (int ni = 0; ni < 4; ni++)
        acc[mi][ni] = __builtin_amdgcn_mfma_f32_16x16x32_bf16(fah[mi], fbl[ni], acc[mi][ni], 0, 0, 0);
  }

  // epilogue: C/D layout (verified m89): col = lane&15, row = (lane>>4)*4 + reg
#pragma unroll
  for (int mi = 0; mi < MI; mi++) {
    const int rb = row0 + wrr + mi * 16 + ((lane >> 4) << 2);
#pragma unroll
    for (int ni = 0; ni < 4; ni++) {
      const int col = col0 + wcc + ni * 16 + (lane & 15);
      f32x4 v = acc[mi][ni];
#pragma unroll
      for (int r = 0; r < 4; r++) {
        float* cp = C + (size_t)(rb + r) * N + col;
        float x = v[r];
        if (MODE == 1) { if (col < nsig) x = sigmoidf_(x); }
        if (MODE == 2) x += *cp;
        *cp = x;
      }
    }
  }
}

// ---------------- depthwise causal conv (K=15) + gate, split output ----------------
// gv: (M,1024): gate(sigmoided)=[0:512), val=[512:1024).
__global__ __launch_bounds__(256) void conv_gate_kernel(const float* __restrict__ gv,
                                                        const float* __restrict__ cw,
                                                        ushort* __restrict__ oh,
                                                        ushort* __restrict__ ol) {
  int d = ((blockIdx.x & 1) << 8) + threadIdx.x;
  int bt = blockIdx.x >> 1;
  int t = bt & (T_ - 1);
  float w[K_];
#pragma unroll
  for (int k = 0; k < K_; k++) w[k] = cw[d * K_ + k];
  const float* val = gv + (size_t)bt * 1024 + 512 + d;
  float s = 0.0f;
#pragma unroll
  for (int k = 0; k < K_; k++) {
    int tt = t - (K_ - 1) + k;
    if (tt >= 0) s = fmaf(w[k], val[(tt - t) * 1024], s);
  }
  float gate = gv[(size_t)bt * 1024 + d];
  float y = s * gate;
  ushort h, l; split2(y, h, l);
  size_t idx = (size_t)bt * 512 + d;
  oh[idx] = h; ol[idx] = l;
}

// ---------------- per-token g(8,sigmoid) / v(32) / rw(8,softmax) from hi/lo h ----------------
__global__ __launch_bounds__(256) void gvr_kernel(const ushort* __restrict__ hh,
                                                  const ushort* __restrict__ hl,
                                                  const float* __restrict__ wg,
                                                  const float* __restrict__ wv,
                                                  const float* __restrict__ rq,
                                                  float* __restrict__ garr,
                                                  float* __restrict__ varr,
                                                  float* __restrict__ rwarr) {
  __shared__ float smem[4][48];
  int w = threadIdx.x >> 6, lane = threadIdx.x & 63;
  int tok = (blockIdx.x << 2) + w;
  size_t off = (size_t)tok * D_ + lane * 8;
  union { uint4 u; ushort s[8]; } H, Lo;
  H.u  = *(const uint4*)(hh + off);
  Lo.u = *(const uint4*)(hl + off);
  float hreg[8];
#pragma unroll
  for (int j = 0; j < 8; j++) hreg[j] = bf2f(H.s[j]) + bf2f(Lo.s[j]);
  float keep = 0.0f;
  for (int o = 0; o < 48; o++) {
    const float* Wr = (o < 8) ? (wg + o * D_)
                    : (o < 40 ? (wv + (o - 8) * D_) : (rq + (o - 40) * D_));
    const float* wp = Wr + lane * 8;
    float p = 0.0f;
#pragma unroll
    for (int j = 0; j < 8; j++) p = fmaf(hreg[j], wp[j], p);
#pragma unroll
    for (int off2 = 32; off2 > 0; off2 >>= 1) p += __shfl_xor(p, off2);
    if (lane == o) keep = p;
  }
  if (lane < 48) smem[w][lane] = keep;
  __syncthreads();
  if (lane < 8)  garr[(size_t)tok * 8 + lane]  = sigmoidf_(smem[w][lane]);
  if (lane < 32) varr[(size_t)tok * 32 + lane] = smem[w][8 + lane];
  if (lane < 8) {
    float q = smem[w][40 + lane];
    float mx = smem[w][40];
#pragma unroll
    for (int j = 1; j < 8; j++) mx = fmaxf(mx, smem[w][40 + j]);
    float sum = 0.0f;
#pragma unroll
    for (int j = 0; j < 8; j++) sum += expf(smem[w][40 + j] - mx);
    rwarr[(size_t)tok * 8 + lane] = expf(q - mx) / sum;
  }
}

// ---------------- sequential scan over T, fused read-weighting, split output ----------------
__global__ __launch_bounds__(256) void scan_kernel(const float* __restrict__ garr,
                                                   const float* __restrict__ varr,
                                                   const float* __restrict__ rwarr,
                                                   ushort* __restrict__ rfh,
                                                   ushort* __restrict__ rfl,
                                                   float* __restrict__ mem) {
  int b = blockIdx.x;
  int tid = threadIdx.x;
  int s = tid >> 5, ds = tid & 31;
  float m = mem[b * 256 + tid];
  const float* gp = garr + (size_t)b * T_ * 8;
  const float* vp = varr + (size_t)b * T_ * 32;
  const float* rp = rwarr + (size_t)b * T_ * 8;
  ushort* rfhp = rfh + (size_t)b * T_ * 256 + tid;
  ushort* rflp = rfl + (size_t)b * T_ * 256 + tid;
  float gn = gp[s], vn = vp[ds], rn = rp[s];
  for (int t = 0; t < T_; t++) {
    float gc = gn, vc = vn, rc = rn;
    if (t + 1 < T_) {
      gn = gp[(t + 1) * 8 + s];
      vn = vp[(t + 1) * 32 + ds];
      rn = rp[(t + 1) * 8 + s];
    }
    m = fmaf(m, 1.0f - gc, gc * vc);
    float y = rc * m;
    ushort h, l; split2(y, h, l);
    rfhp[(size_t)t * 256] = h;
    rflp[(size_t)t * 256] = l;
  }
  mem[b * 256 + tid] = m;
}

// ---------------- FFN activation: silu(gate)*up -> hi/lo planes ----------------
// c: (M, 4096) fp32: cols [0:2048) = gate, [2048:4096) = up. out planes: (M, 2048)
__global__ __launch_bounds__(256) void ffn_act_kernel(const float* __restrict__ c,
                                                      ushort* __restrict__ hi,
                                                      ushort* __restrict__ lo) {
  int i = blockIdx.x * 256 + threadIdx.x;      // over M*2048/4
  int row = i >> 9, cf = (i & 511) * 4;
  const float4 g = *(const float4*)(c + (size_t)row * 4096 + cf);
  const float4 u = *(const float4*)(c + (size_t)row * 4096 + 2048 + cf);
  float y[4] = { siluf_(g.x) * u.x, siluf_(g.y) * u.y,
                 siluf_(g.z) * u.z, siluf_(g.w) * u.w };
  ushort h[4], l[4];
#pragma unroll
  for (int j = 0; j < 4; j++) split2(y[j], h[j], l[j]);
  ((ushort4*)hi)[i] = *(ushort4*)h;
  ((ushort4*)lo)[i] = *(ushort4*)l;
}

// ---------------- launch ----------------
extern "C" void kernel_launch(void* const* d_in, const int* in_sizes, int n_in,
                              void* d_out, int out_size, void* d_ws, size_t ws_size,
                              hipStream_t stream) {
  const int*   tokens     = (const int*)d_in[0];
  const float* embed      = (const float*)d_in[1];
  const float* ln_in      = (const float*)d_in[2];
  const float* ln1        = (const float*)d_in[3];
  const float* mixer_up   = (const float*)d_in[4];
  const float* conv_w     = (const float*)d_in[5];
  const float* mixer_down = (const float*)d_in[6];
  const float* ln_mem     = (const float*)d_in[7];
  const float* wg         = (const float*)d_in[8];
  const float* wv         = (const float*)d_in[9];
  const float* rq         = (const float*)d_in[10];
  const float* ro         = (const float*)d_in[11];
  const float* ln2        = (const float*)d_in[12];
  const float* Wgf        = (const float*)d_in[13];
  const float* Wuf        = (const float*)d_in[14];
  const float* Wof        = (const float*)d_in[15];
  const float* ln_out     = (const float*)d_in[16];
  float* out = (float*)d_out;

  char* wptr = (char*)d_ws;
  auto alloc = [&](size_t bytes) { void* r = wptr; wptr += (bytes + 255) & ~(size_t)255; return r; };
  float*  bx   = (float*)alloc((size_t)M_ * D_ * 4);
  ushort* bhh  = (ushort*)alloc((size_t)M_ * D_ * 2);
  ushort* bhl  = (ushort*)alloc((size_t)M_ * D_ * 2);
  float*  bgv  = (float*)alloc((size_t)M_ * 1024 * 4);      // 16 MB  (aliased by embed planes after loop)
  float*  bupc = (float*)alloc((size_t)M_ * 4096 * 4);      // 64 MB  (alias region cont.)
  ushort* bcoh = (ushort*)alloc((size_t)M_ * D_ * 2);
  ushort* bcol = (ushort*)alloc((size_t)M_ * D_ * 2);
  ushort* buph = (ushort*)alloc((size_t)M_ * FF_ * 2);
  ushort* bupl = (ushort*)alloc((size_t)M_ * FF_ * 2);
  ushort* brfh = (ushort*)alloc((size_t)M_ * 256 * 2);
  ushort* brfl = (ushort*)alloc((size_t)M_ * 256 * 2);
  float*  bg   = (float*)alloc((size_t)M_ * 8 * 4);
  float*  bv   = (float*)alloc((size_t)M_ * 32 * 4);
  float*  brw  = (float*)alloc((size_t)M_ * 8 * 4);
  float*  bmem = (float*)alloc(B_ * 256 * 4);
  // per-layer weight planes (reused every layer)
  ushort* muh  = (ushort*)alloc((size_t)1024 * 512 * 2);
  ushort* mul2 = (ushort*)alloc((size_t)1024 * 512 * 2);
  ushort* mdh  = (ushort*)alloc((size_t)512 * 512 * 2);
  ushort* mdl  = (ushort*)alloc((size_t)512 * 512 * 2);
  ushort* rh   = (ushort*)alloc((size_t)512 * 256 * 2);
  ushort* rl   = (ushort*)alloc((size_t)512 * 256 * 2);
  ushort* fh   = (ushort*)alloc((size_t)2 * FF_ * 512 * 2); // [Wgf;Wuf] concat, N=4096
  ushort* fl   = (ushort*)alloc((size_t)2 * FF_ * 512 * 2);
  ushort* ohp  = (ushort*)alloc((size_t)512 * FF_ * 2);
  ushort* olp  = (ushort*)alloc((size_t)512 * FF_ * 2);
  // embed planes alias bgv+bupc (80 MB region, need 65.5 MB) — used only after the layer loop
  ushort* eh = (ushort*)bgv;
  ushort* el = eh + (size_t)V_ * D_;

  zero512_kernel<<<1, 512, 0, stream>>>(bmem);
  embed_rms_kernel<<<M_ / 4, 256, 0, stream>>>(tokens, embed, ln_in, bx);

  for (int i = 0; i < L_; i++) {
    wsplit_kernel<<<3968, 256, 0, stream>>>(
        mixer_up + (size_t)i * 1024 * 512, mixer_down + (size_t)i * 512 * 512,
        ro + (size_t)i * 512 * 256, Wgf + (size_t)i * FF_ * 512,
        Wuf + (size_t)i * FF_ * 512, Wof + (size_t)i * 512 * FF_,
        muh, mul2, mdh, mdl, rh, rl, fh, fl, ohp, olp);

    rms_split_kernel<<<M_ / 4, 256, 0, stream>>>(bx, ln1 + i * D_, bhh, bhl);
    gemm_m<1, 128><<<dim3(M_ / 128, 1024 / 128), 256, 0, stream>>>(
        bhh, bhl, muh, mul2, bgv, 1024, 512, 512);
    conv_gate_kernel<<<M_ * 2, 256, 0, stream>>>(bgv, conv_w + (size_t)i * D_ * K_, bcoh, bcol);
    gemm_m<2, 64><<<dim3(M_ / 64, 512 / 128), 256, 0, stream>>>(
        bcoh, bcol, mdh, mdl, bx, 512, 512, 0);

    rms_split_kernel<<<M_ / 4, 256, 0, stream>>>(bx, ln_mem + i * D_, bhh, bhl);
    gvr_kernel<<<M_ / 4, 256, 0, stream>>>(bhh, bhl, wg + (size_t)i * S_ * D_,
                                           wv + (size_t)i * DS_ * D_,
                                           rq + (size_t)i * S_ * D_, bg, bv, brw);
    scan_kernel<<<B_, 256, 0, stream>>>(bg, bv, brw, brfh, brfl, bmem);
    gemm_m<2, 64><<<dim3(M_ / 64, 512 / 128), 256, 0, stream>>>(
        brfh, brfl, rh, rl, bx, 512, 256, 0);

    rms_split_kernel<<<M_ / 4, 256, 0, stream>>>(bx, ln2 + i * D_, bhh, bhl);
    gemm_m<0, 128><<<dim3(M_ / 128, 4096 / 128), 256, 0, stream>>>(
        bhh, bhl, fh, fl, bupc, 4096, 512, 0);
    ffn_act_kernel<<<(M_ * FF_ / 4) / 256, 256, 0, stream>>>(bupc, buph, bupl);
    gemm_m<2, 64><<<dim3(M_ / 64, 512 / 128), 256, 0, stream>>>(
        buph, bupl, ohp, olp, bx, 512, 2048, 0);
  }

  // head: convert embed to planes (aliases bgv/bupc — both dead now), then big GEMM
  split4_kernel<<<((size_t)V_ * D_ / 4 + 255) / 256, 256, 0, stream>>>(embed, eh, el, V_ * D_ / 4);
  rms_split_kernel<<<M_ / 4, 256, 0, stream>>>(bx, ln_out, bhh, bhl);
  gemm_m<0, 128><<<dim3(M_ / 128, V_ / 128), 256, 0, stream>>>(
      bhh, bhl, eh, el, out, V_, 512, 0);
}